// Round 1
// baseline (5195.858 us; speedup 1.0000x reference)
//
#include <hip/hip_runtime.h>
#include <hip/hip_bf16.h>
#include <math.h>

// Problem constants (reference: LinearAttentionNeuralOperator)
constexpr int NP  = 32768;  // mesh points
constexpr int DD  = 256;    // n_hidden
constexpr int HH  = 8;      // heads
constexpr int DHH = 32;     // dim_head
constexpr int QKD = 128;    // q/k feature dim

__device__ __forceinline__ float gelu_f(float x) {
    return 0.5f * x * (1.0f + erff(x * 0.70710678118654752f));
}

// ---------------------------------------------------------------------------
// Generic fused GEMM: C = epilogue( A' @ W + bias (+bias2) )  with
//   A' = LN(A) (LNIN, using row sum/sumsq partials)  or generated GELU(x@w1+b1) (GENA)
//   epilogue: optional GELU, optional residual (+= Cout), optional row-stats
//   emit (sum, sumsq partial per col-block), optional head-permuted store.
// BM=64 rows, BN=128 cols (grid.y=2), BK=64. 256 threads.
// ---------------------------------------------------------------------------
template<bool GENA, bool LNIN, bool DOGELU, bool RESID, bool STATS, bool PERM>
__global__ __launch_bounds__(256) void gemm_k(
    const float* __restrict__ A,        // [NP,K] (unused if GENA)
    const float* __restrict__ W,        // [K,256]
    const float* __restrict__ bias,     // [256]
    const float* __restrict__ bias2,    // [256] or nullptr
    float* __restrict__ Cout,           // [NP,256]  (PERM: [8][NP][32])
    const float* __restrict__ stats_in, // [NP*4] (LNIN)
    float* __restrict__ stats_out,      // [NP*4] (STATS)
    const float* __restrict__ lng, const float* __restrict__ lnb,
    const float* __restrict__ genx,     // [NP,3]   (GENA)
    const float* __restrict__ genw1,    // [3,512]  (GENA)
    const float* __restrict__ genb1,    // [512]    (GENA)
    int K)
{
    __shared__ float As[64][68];    // [k][row], pad 68 (272B rows, 16B aligned)
    __shared__ float Ws[64][132];   // [k][col], pad 132
    __shared__ float extra[GENA ? 2304 : 4]; // GENA: xs[64*4] | w1[3*512] | b1[512]

    const int tid   = threadIdx.x;
    const int rBase = blockIdx.x * 64;
    const int cBase = blockIdx.y * 128;
    const int c0 = (tid & 31) * 4;   // 4 output cols
    const int r0 = (tid >> 5) * 8;   // 8 output rows

    if constexpr (GENA) {
        for (int it = tid; it < 192; it += 256)
            extra[(it / 3) * 4 + (it % 3)] = genx[(size_t)(rBase + it / 3) * 3 + (it % 3)];
        for (int it = tid; it < 1536; it += 256) extra[256 + it]  = genw1[it];
        for (int it = tid; it < 512;  it += 256) extra[1792 + it] = genb1[it];
        __syncthreads();
    }

    float4 acc[8];
    #pragma unroll
    for (int i = 0; i < 8; ++i) { acc[i].x = 0.f; acc[i].y = 0.f; acc[i].z = 0.f; acc[i].w = 0.f; }

    for (int kc = 0; kc < K; kc += 64) {
        // ---- stage A chunk (transposed into LDS) ----
        if constexpr (GENA) {
            #pragma unroll
            for (int it = 0; it < 16; ++it) {
                int idx = tid + it * 256;
                int kk = idx & 63, row = idx >> 6;
                float v = extra[row * 4 + 0] * extra[256 + kc + kk]
                        + extra[row * 4 + 1] * extra[256 + 512 + kc + kk]
                        + extra[row * 4 + 2] * extra[256 + 1024 + kc + kk]
                        + extra[1792 + kc + kk];
                As[kk][row] = gelu_f(v);
            }
        } else {
            #pragma unroll
            for (int it = 0; it < 4; ++it) {
                int row = (tid >> 4) + it * 16;
                int kk  = (tid & 15) * 4;
                float4 av = *(const float4*)(A + (size_t)(rBase + row) * K + kc + kk);
                if constexpr (LNIN) {
                    float4 s4 = *(const float4*)(stats_in + (size_t)(rBase + row) * 4);
                    float mean = (s4.x + s4.z) * 0.00390625f;
                    float ex2  = (s4.y + s4.w) * 0.00390625f;
                    float rstd = rsqrtf(fmaxf(ex2 - mean * mean, 0.f) + 1e-5f);
                    float4 gg = *(const float4*)(lng + kc + kk);
                    float4 bb = *(const float4*)(lnb + kc + kk);
                    av.x = (av.x - mean) * rstd * gg.x + bb.x;
                    av.y = (av.y - mean) * rstd * gg.y + bb.y;
                    av.z = (av.z - mean) * rstd * gg.z + bb.z;
                    av.w = (av.w - mean) * rstd * gg.w + bb.w;
                }
                As[kk + 0][row] = av.x; As[kk + 1][row] = av.y;
                As[kk + 2][row] = av.z; As[kk + 3][row] = av.w;
            }
        }
        // ---- stage W chunk ----
        #pragma unroll
        for (int it = 0; it < 8; ++it) {
            int kk = (tid >> 5) + it * 8;
            int cc = (tid & 31) * 4;
            *(float4*)&Ws[kk][cc] = *(const float4*)(W + (size_t)(kc + kk) * 256 + cBase + cc);
        }
        __syncthreads();
        // ---- inner product ----
        #pragma unroll 16
        for (int k = 0; k < 64; ++k) {
            float4 wv = *(float4*)&Ws[k][c0];
            float4 a0 = *(float4*)&As[k][r0];
            float4 a1 = *(float4*)&As[k][r0 + 4];
            acc[0].x += a0.x * wv.x; acc[0].y += a0.x * wv.y; acc[0].z += a0.x * wv.z; acc[0].w += a0.x * wv.w;
            acc[1].x += a0.y * wv.x; acc[1].y += a0.y * wv.y; acc[1].z += a0.y * wv.z; acc[1].w += a0.y * wv.w;
            acc[2].x += a0.z * wv.x; acc[2].y += a0.z * wv.y; acc[2].z += a0.z * wv.z; acc[2].w += a0.z * wv.w;
            acc[3].x += a0.w * wv.x; acc[3].y += a0.w * wv.y; acc[3].z += a0.w * wv.z; acc[3].w += a0.w * wv.w;
            acc[4].x += a1.x * wv.x; acc[4].y += a1.x * wv.y; acc[4].z += a1.x * wv.z; acc[4].w += a1.x * wv.w;
            acc[5].x += a1.y * wv.x; acc[5].y += a1.y * wv.y; acc[5].z += a1.y * wv.z; acc[5].w += a1.y * wv.w;
            acc[6].x += a1.z * wv.x; acc[6].y += a1.z * wv.y; acc[6].z += a1.z * wv.z; acc[6].w += a1.z * wv.w;
            acc[7].x += a1.w * wv.x; acc[7].y += a1.w * wv.y; acc[7].z += a1.w * wv.z; acc[7].w += a1.w * wv.w;
        }
        __syncthreads();
    }

    // ---- epilogue ----
    float4 bb = *(const float4*)(bias + cBase + c0);
    if (bias2) {
        float4 b2 = *(const float4*)(bias2 + cBase + c0);
        bb.x += b2.x; bb.y += b2.y; bb.z += b2.z; bb.w += b2.w;
    }
    #pragma unroll
    for (int i = 0; i < 8; ++i) {
        int grow = rBase + r0 + i;
        float vx = acc[i].x + bb.x, vy = acc[i].y + bb.y, vz = acc[i].z + bb.z, vw = acc[i].w + bb.w;
        if constexpr (DOGELU) { vx = gelu_f(vx); vy = gelu_f(vy); vz = gelu_f(vz); vw = gelu_f(vw); }
        if constexpr (RESID) {
            float4 old = *(const float4*)(Cout + (size_t)grow * 256 + cBase + c0);
            vx += old.x; vy += old.y; vz += old.z; vw += old.w;
        }
        if constexpr (STATS) {
            float rs = vx + vy + vz + vw;
            float rq = vx * vx + vy * vy + vz * vz + vw * vw;
            #pragma unroll
            for (int m = 1; m < 32; m <<= 1) { rs += __shfl_xor(rs, m); rq += __shfl_xor(rq, m); }
            if ((tid & 31) == 0) {
                stats_out[(size_t)grow * 4 + blockIdx.y * 2 + 0] = rs;
                stats_out[(size_t)grow * 4 + blockIdx.y * 2 + 1] = rq;
            }
        }
        float4 ov; ov.x = vx; ov.y = vy; ov.z = vz; ov.w = vw;
        if constexpr (PERM) {
            int cg = cBase + c0;
            int h = cg >> 5, j = cg & 31;
            *(float4*)(Cout + (size_t)h * NP * 32 + (size_t)grow * 32 + j) = ov;
        } else {
            *(float4*)(Cout + (size_t)grow * 256 + cBase + c0) = ov;
        }
    }
}

// ---------------------------------------------------------------------------
// kv_kernel: per (head, 512-row chunk): recompute k-logits & v from xm2,
// e = exp(k_l/tk) (no max-sub: logits ~ N(0,0.1^2); clamped for safety),
// accumulate kvU[h,128,32] and sumexp[h,128] via fp32 atomics.
// ---------------------------------------------------------------------------
__global__ __launch_bounds__(256) void kv_kernel(
    const float* __restrict__ xm2,   // [8][NP][32]
    const float* __restrict__ wk,    // [32][128]
    const float* __restrict__ wv,    // [32][32]
    const float* __restrict__ tk_arr,
    float* __restrict__ kvU, float* __restrict__ sumexp, int layer)
{
    const int tid = threadIdx.x;
    const int h = blockIdx.y;
    const int rowBase = blockIdx.x * 512;
    __shared__ float xs[64][36];
    __shared__ float wks[32 * 128];
    __shared__ float wvs[32 * 32];
    __shared__ float es[64][128];
    __shared__ float vs[64][32];
    __shared__ float sume[128];

    float tk = fminf(fmaxf(tk_arr[layer * 8 + h], 0.1f), 2.0f);
    float invtk = 1.0f / tk;
    for (int idx = tid; idx < 4096; idx += 256) wks[idx] = wk[idx];
    for (int idx = tid; idx < 1024; idx += 256) wvs[idx] = wv[idx];
    if (tid < 128) sume[tid] = 0.f;

    float kvacc[4][4] = {};
    float seacc[4] = {0.f, 0.f, 0.f, 0.f};
    const int d0 = (tid & 31) * 4;
    const int c0 = (tid >> 5) * 4;
    const float* src = xm2 + (size_t)h * NP * 32 + (size_t)rowBase * 32;
    __syncthreads();

    for (int sub = 0; sub < 8; ++sub) {
        #pragma unroll
        for (int it = 0; it < 2; ++it) {
            int fid = tid + it * 256;
            int row = fid >> 3, col = (fid & 7) * 4;
            *(float4*)&xs[row][col] = *(const float4*)(src + (size_t)(sub * 64 + row) * 32 + col);
        }
        __syncthreads();
        // e = exp(k_logit * invtk)
        #pragma unroll
        for (int p = 0; p < 8; ++p) {
            int n = (tid >> 5) + p * 8;
            float a0 = 0.f, a1 = 0.f, a2 = 0.f, a3 = 0.f;
            #pragma unroll
            for (int j = 0; j < 32; ++j) {
                float xv = xs[n][j];
                float4 w4 = *(const float4*)&wks[j * 128 + d0];
                a0 += xv * w4.x; a1 += xv * w4.y; a2 += xv * w4.z; a3 += xv * w4.w;
            }
            float4 e4;
            e4.x = __expf(fminf(fmaxf(a0 * invtk, -60.f), 60.f));
            e4.y = __expf(fminf(fmaxf(a1 * invtk, -60.f), 60.f));
            e4.z = __expf(fminf(fmaxf(a2 * invtk, -60.f), 60.f));
            e4.w = __expf(fminf(fmaxf(a3 * invtk, -60.f), 60.f));
            *(float4*)&es[n][d0] = e4;
            seacc[0] += e4.x; seacc[1] += e4.y; seacc[2] += e4.z; seacc[3] += e4.w;
        }
        // v
        #pragma unroll
        for (int p = 0; p < 2; ++p) {
            int n = (tid >> 3) + p * 32;
            int cv = (tid & 7) * 4;
            float a0 = 0.f, a1 = 0.f, a2 = 0.f, a3 = 0.f;
            #pragma unroll
            for (int j = 0; j < 32; ++j) {
                float xv = xs[n][j];
                float4 w4 = *(const float4*)&wvs[j * 32 + cv];
                a0 += xv * w4.x; a1 += xv * w4.y; a2 += xv * w4.z; a3 += xv * w4.w;
            }
            float4 v4; v4.x = a0; v4.y = a1; v4.z = a2; v4.w = a3;
            *(float4*)&vs[n][cv] = v4;
        }
        __syncthreads();
        // kv += e^T v
        #pragma unroll 8
        for (int n = 0; n < 64; ++n) {
            float4 e4 = *(float4*)&es[n][d0];
            float4 v4 = *(float4*)&vs[n][c0];
            kvacc[0][0] += e4.x * v4.x; kvacc[0][1] += e4.x * v4.y; kvacc[0][2] += e4.x * v4.z; kvacc[0][3] += e4.x * v4.w;
            kvacc[1][0] += e4.y * v4.x; kvacc[1][1] += e4.y * v4.y; kvacc[1][2] += e4.y * v4.z; kvacc[1][3] += e4.y * v4.w;
            kvacc[2][0] += e4.z * v4.x; kvacc[2][1] += e4.z * v4.y; kvacc[2][2] += e4.z * v4.z; kvacc[2][3] += e4.z * v4.w;
            kvacc[3][0] += e4.w * v4.x; kvacc[3][1] += e4.w * v4.y; kvacc[3][2] += e4.w * v4.z; kvacc[3][3] += e4.w * v4.w;
        }
        __syncthreads();
    }
    atomicAdd(&sume[d0 + 0], seacc[0]); atomicAdd(&sume[d0 + 1], seacc[1]);
    atomicAdd(&sume[d0 + 2], seacc[2]); atomicAdd(&sume[d0 + 3], seacc[3]);
    __syncthreads();
    if (tid < 128) atomicAdd(&sumexp[h * 128 + tid], sume[tid]);
    #pragma unroll
    for (int di = 0; di < 4; ++di)
        #pragma unroll
        for (int ci = 0; ci < 4; ++ci)
            atomicAdd(&kvU[(size_t)h * 4096 + (size_t)(d0 + di) * 32 + (c0 + ci)], kvacc[di][ci]);
}

// ---------------------------------------------------------------------------
// qkv_kernel: per (head, 64-row tile): q logits -> softmax(dim=128) -> /sumexp
// -> @ kvU -> write [N,256] layout (col h*32+c).
// ---------------------------------------------------------------------------
__global__ __launch_bounds__(256) void qkv_kernel(
    const float* __restrict__ xm2, const float* __restrict__ wq,
    const float* __restrict__ tq_arr,
    const float* __restrict__ kvU, const float* __restrict__ sumexp,
    float* __restrict__ outD, int layer)
{
    const int tid = threadIdx.x;
    const int h = blockIdx.y;
    const int nb = blockIdx.x * 64;
    __shared__ float xs[64][36];
    __shared__ float wqs[32 * 128];
    __shared__ float qs[64][132];
    __shared__ float kvs[128 * 32];
    __shared__ float ises[128];

    float tq = fminf(fmaxf(tq_arr[layer * 8 + h], 0.1f), 2.0f);
    float invtq = 1.0f / tq;
    for (int idx = tid; idx < 4096; idx += 256) wqs[idx] = wq[idx];
    for (int idx = tid; idx < 4096; idx += 256) kvs[idx] = kvU[(size_t)h * 4096 + idx];
    if (tid < 128) ises[tid] = 1.0f / sumexp[h * 128 + tid];
    const float* src = xm2 + (size_t)h * NP * 32 + (size_t)nb * 32;
    #pragma unroll
    for (int it = 0; it < 2; ++it) {
        int fid = tid + it * 256;
        int row = fid >> 3, col = (fid & 7) * 4;
        *(float4*)&xs[row][col] = *(const float4*)(src + (size_t)row * 32 + col);
    }
    __syncthreads();

    const int d0 = (tid & 31) * 4;
    #pragma unroll
    for (int p = 0; p < 8; ++p) {
        int n = (tid >> 5) + p * 8;
        float a0 = 0.f, a1 = 0.f, a2 = 0.f, a3 = 0.f;
        #pragma unroll
        for (int j = 0; j < 32; ++j) {
            float xv = xs[n][j];
            float4 w4 = *(const float4*)&wqs[j * 128 + d0];
            a0 += xv * w4.x; a1 += xv * w4.y; a2 += xv * w4.z; a3 += xv * w4.w;
        }
        float4 q4; q4.x = a0 * invtq; q4.y = a1 * invtq; q4.z = a2 * invtq; q4.w = a3 * invtq;
        *(float4*)&qs[n][d0] = q4;
    }
    __syncthreads();
    if (tid < 64) {
        float m = -1e30f;
        #pragma unroll
        for (int j = 0; j < 32; ++j) {
            float4 q4 = *(float4*)&qs[tid][j * 4];
            m = fmaxf(m, fmaxf(fmaxf(q4.x, q4.y), fmaxf(q4.z, q4.w)));
        }
        float s = 0.f;
        #pragma unroll
        for (int j = 0; j < 32; ++j) {
            float4 q4 = *(float4*)&qs[tid][j * 4];
            q4.x = __expf(q4.x - m); q4.y = __expf(q4.y - m);
            q4.z = __expf(q4.z - m); q4.w = __expf(q4.w - m);
            s += q4.x + q4.y + q4.z + q4.w;
            *(float4*)&qs[tid][j * 4] = q4;
        }
        float inv = 1.0f / s;
        #pragma unroll
        for (int j = 0; j < 32; ++j) {
            float4 q4 = *(float4*)&qs[tid][j * 4];
            float4 i4 = *(float4*)&ises[j * 4];
            q4.x *= inv * i4.x; q4.y *= inv * i4.y; q4.z *= inv * i4.z; q4.w *= inv * i4.w;
            *(float4*)&qs[tid][j * 4] = q4;
        }
    }
    __syncthreads();
    {
        int n  = (tid >> 3);
        int cv = (tid & 7) * 4;
        float4 accA; accA.x = accA.y = accA.z = accA.w = 0.f;
        float4 accB; accB.x = accB.y = accB.z = accB.w = 0.f;
        #pragma unroll 16
        for (int d = 0; d < 128; ++d) {
            float qa = qs[n][d];
            float qb = qs[n + 32][d];
            float4 k4 = *(const float4*)&kvs[d * 32 + cv];
            accA.x += qa * k4.x; accA.y += qa * k4.y; accA.z += qa * k4.z; accA.w += qa * k4.w;
            accB.x += qb * k4.x; accB.y += qb * k4.y; accB.z += qb * k4.z; accB.w += qb * k4.w;
        }
        *(float4*)(outD + (size_t)(nb + n) * 256 + h * 32 + cv) = accA;
        *(float4*)(outD + (size_t)(nb + n + 32) * 256 + h * 32 + cv) = accB;
    }
}

// ---------------------------------------------------------------------------
// head: out[n] = LN(fx[n]; ln3) . head_w + head_b   (one wave per row)
// ---------------------------------------------------------------------------
__global__ __launch_bounds__(256) void head_kernel(
    const float* __restrict__ fx, const float* __restrict__ g, const float* __restrict__ b,
    const float* __restrict__ hw, const float* __restrict__ hb, float* __restrict__ out)
{
    int lane = threadIdx.x & 63;
    int row = blockIdx.x * 4 + (threadIdx.x >> 6);
    float4 v = *(const float4*)(fx + (size_t)row * 256 + lane * 4);
    float s1 = v.x + v.y + v.z + v.w;
    float s2 = v.x * v.x + v.y * v.y + v.z * v.z + v.w * v.w;
    #pragma unroll
    for (int m = 1; m < 64; m <<= 1) { s1 += __shfl_xor(s1, m); s2 += __shfl_xor(s2, m); }
    float mean = s1 * 0.00390625f;
    float rstd = rsqrtf(fmaxf(s2 * 0.00390625f - mean * mean, 0.f) + 1e-5f);
    float4 gg = *(const float4*)(g + lane * 4);
    float4 bb = *(const float4*)(b + lane * 4);
    float4 w4 = *(const float4*)(hw + lane * 4);
    float d = ((v.x - mean) * rstd * gg.x + bb.x) * w4.x
            + ((v.y - mean) * rstd * gg.y + bb.y) * w4.y
            + ((v.z - mean) * rstd * gg.z + bb.z) * w4.z
            + ((v.w - mean) * rstd * gg.w + bb.w) * w4.w;
    #pragma unroll
    for (int m = 1; m < 64; m <<= 1) d += __shfl_xor(d, m);
    if (lane == 0) out[row] = d + hb[0];
}

extern "C" void kernel_launch(void* const* d_in, const int* in_sizes, int n_in,
                              void* d_out, int out_size, void* d_ws, size_t ws_size,
                              hipStream_t stream)
{
    const float* x      = (const float*)d_in[0];
    const float* pre_w1 = (const float*)d_in[1];
    const float* pre_b1 = (const float*)d_in[2];
    const float* pre_w2 = (const float*)d_in[3];
    const float* pre_b2 = (const float*)d_in[4];
    const float* ph     = (const float*)d_in[5];
    const float* ln1_g  = (const float*)d_in[6];
    const float* ln1_b  = (const float*)d_in[7];
    const float* inp_w  = (const float*)d_in[8];
    const float* inp_b  = (const float*)d_in[9];
    const float* temp_q = (const float*)d_in[10];
    const float* temp_k = (const float*)d_in[11];
    const float* wq     = (const float*)d_in[12];
    const float* wk     = (const float*)d_in[13];
    const float* wv     = (const float*)d_in[14];
    const float* out_w1 = (const float*)d_in[15];
    const float* out_b1 = (const float*)d_in[16];
    const float* out_w2 = (const float*)d_in[17];
    const float* out_b2 = (const float*)d_in[18];
    const float* ln2_g  = (const float*)d_in[19];
    const float* ln2_b  = (const float*)d_in[20];
    const float* mlp_w1 = (const float*)d_in[21];
    const float* mlp_b1 = (const float*)d_in[22];
    const float* mlp_w2 = (const float*)d_in[23];
    const float* mlp_b2 = (const float*)d_in[24];
    const float* ln3_g  = (const float*)d_in[25];
    const float* ln3_b  = (const float*)d_in[26];
    const float* head_w = (const float*)d_in[27];
    const float* head_b = (const float*)d_in[28];
    float* out = (float*)d_out;

    // workspace layout (fp32): fx | C(xm2/attn-mid) | Dt | stats | kvU | sumexp
    float* fx = (float*)d_ws;
    float* C  = fx + (size_t)NP * 256;
    float* Dt = C  + (size_t)NP * 256;
    float* st = Dt + (size_t)NP * 256;
    float* kv = st + (size_t)NP * 4;
    float* se = kv + 8 * 128 * 32;

    dim3 gg(512, 2), bt(256);

    // preprocess: fx = GELU(x@pre_w1+pre_b1)@pre_w2 + pre_b2 + placeholder  (+stats)
    gemm_k<true, false, false, false, true, false><<<gg, bt, 0, stream>>>(
        nullptr, pre_w2, pre_b2, ph, fx, nullptr, st, nullptr, nullptr,
        x, pre_w1, pre_b1, 512);

    for (int i = 0; i < 5; ++i) {
        // xm2 = perm( LN(fx;ln1) @ inp_w + inp_b )
        gemm_k<false, true, false, false, false, true><<<gg, bt, 0, stream>>>(
            fx, inp_w + (size_t)i * 65536, inp_b + i * 256, nullptr, C, st, nullptr,
            ln1_g + i * 256, ln1_b + i * 256, nullptr, nullptr, nullptr, 256);
        // kv stats
        hipMemsetAsync(kv, 0, (8 * 128 * 32 + 8 * 128) * sizeof(float), stream);
        kv_kernel<<<dim3(64, 8), bt, 0, stream>>>(C, wk + (size_t)i * 4096, wv + (size_t)i * 1024,
                                                  temp_k, kv, se, i);
        // qkv -> Dt [N,256]
        qkv_kernel<<<dim3(512, 8), bt, 0, stream>>>(C, wq + (size_t)i * 4096, temp_q, kv, se, Dt, i);
        // C = GELU(Dt @ out_w1 + out_b1)
        gemm_k<false, false, true, false, false, false><<<gg, bt, 0, stream>>>(
            Dt, out_w1 + (size_t)i * 65536, out_b1 + i * 256, nullptr, C, nullptr, nullptr,
            nullptr, nullptr, nullptr, nullptr, nullptr, 256);
        // fx += C @ out_w2 + out_b2   (+stats for ln2)
        gemm_k<false, false, false, true, true, false><<<gg, bt, 0, stream>>>(
            C, out_w2 + (size_t)i * 65536, out_b2 + i * 256, nullptr, fx, nullptr, st,
            nullptr, nullptr, nullptr, nullptr, nullptr, 256);
        // Dt = GELU( LN(fx;ln2) @ mlp_w1 + mlp_b1 )
        gemm_k<false, true, true, false, false, false><<<gg, bt, 0, stream>>>(
            fx, mlp_w1 + (size_t)i * 65536, mlp_b1 + i * 256, nullptr, Dt, st, nullptr,
            ln2_g + i * 256, ln2_b + i * 256, nullptr, nullptr, nullptr, 256);
        // fx += Dt @ mlp_w2 + mlp_b2  (+stats for next ln1)
        gemm_k<false, false, false, true, true, false><<<gg, bt, 0, stream>>>(
            Dt, mlp_w2 + (size_t)i * 65536, mlp_b2 + i * 256, nullptr, fx, nullptr, st,
            nullptr, nullptr, nullptr, nullptr, nullptr, 256);
    }
    head_kernel<<<dim3(NP / 4), bt, 0, stream>>>(fx, ln3_g, ln3_b, head_w, head_b, out);
}